// Round 1
// baseline (130.895 us; speedup 1.0000x reference)
//
#include <hip/hip_runtime.h>
#include <math.h>

#define B_SZ 2048
#define R_SZ 64
#define Q_TILE 4

// B^-0.2 for B=2048: 2^(-2.2)
#define B_POW_NEG02 0.217637640824031f
#define SQRT_2PI 2.5066282746310002f

// ---------------------------------------------------------------------------
// Kernel 1: per-receptor stats -> mean[r], kscale[r] = sqrt(0.5)/h, lscale[r]
// ---------------------------------------------------------------------------
__global__ __launch_bounds__(256) void stats_kernel(const float* __restrict__ A,
                                                    float* __restrict__ mean,
                                                    float* __restrict__ kscale,
                                                    float* __restrict__ lscale) {
    int r = blockIdx.x;
    int tid = threadIdx.x;
    float s = 0.f, s2 = 0.f;
    for (int b = tid; b < B_SZ; b += 256) {
        float v = A[b * R_SZ + r];
        s += v;
        s2 += v * v;
    }
    for (int off = 32; off > 0; off >>= 1) {
        s += __shfl_down(s, off, 64);
        s2 += __shfl_down(s2, off, 64);
    }
    __shared__ float ls[4], ls2[4];
    int wave = tid >> 6, lane = tid & 63;
    if (lane == 0) { ls[wave] = s; ls2[wave] = s2; }
    __syncthreads();
    if (tid == 0) {
        s = ls[0] + ls[1] + ls[2] + ls[3];
        s2 = ls2[0] + ls2[1] + ls2[2] + ls2[3];
        float m = s / (float)B_SZ;
        float var = (s2 - s * m) / (float)(B_SZ - 1);   // ddof=1
        var = fmaxf(var, 0.f);
        float stdv = sqrtf(var);
        float h = fmaxf(1.06f * stdv * B_POW_NEG02, 1e-4f);
        mean[r] = m;
        kscale[r] = sqrtf(0.5f) / h;                     // (d*k)^2 = 0.5*(d/h)^2
        lscale[r] = 1.0f / ((float)B_SZ * h * SQRT_2PI);
    }
}

// ---------------------------------------------------------------------------
// Kernel 2: partial Gram matrix G[i][j] += sum_b A[b][i]*A[b][j]
// grid (64, 4): blockIdx.x = i, blockIdx.y = quarter of the b-range
// ---------------------------------------------------------------------------
__global__ __launch_bounds__(256) void gram_kernel(const float* __restrict__ A,
                                                   float* __restrict__ G) {
    int i = blockIdx.x;
    int bq = blockIdx.y;
    int tid = threadIdx.x;
    int j = tid & 63, bg = tid >> 6;
    float acc = 0.f;
    int bend = bq * 512 + 512;
    for (int b = bq * 512 + bg; b < bend; b += 4) {
        acc += A[b * R_SZ + i] * A[b * R_SZ + j];
    }
    __shared__ float red[4][64];
    red[bg][j] = acc;
    __syncthreads();
    if (tid < 64) {
        float ssum = red[0][tid] + red[1][tid] + red[2][tid] + red[3][tid];
        atomicAdd(&G[i * 64 + tid], ssum);
    }
}

// ---------------------------------------------------------------------------
// Kernel 3: cov from Gram + means, accumulate sum of squared off-diagonals
// ---------------------------------------------------------------------------
__global__ __launch_bounds__(64) void cov_finalize(const float* __restrict__ G,
                                                   const float* __restrict__ mean,
                                                   float* __restrict__ out) {
    int i = blockIdx.x, j = threadIdx.x;
    float g = G[i * 64 + j];
    float cov = (g - (float)B_SZ * mean[i] * mean[j]) / (float)(B_SZ - 1);
    float v = (i == j) ? 0.f : cov * cov;
    for (int off = 32; off > 0; off >>= 1) v += __shfl_down(v, off, 64);
    if (j == 0) atomicAdd(out, v);   // COV_WEIGHT = 1.0
}

// ---------------------------------------------------------------------------
// Kernel 4: pairwise KDE + entropy accumulation.
// grid 512 blocks x 256 threads. Block handles Q_TILE=4 query rows.
// lane -> receptor r (coalesced row loads), 4 sample-groups stride the s loop.
// ---------------------------------------------------------------------------
__global__ __launch_bounds__(256) void kde_kernel(const float* __restrict__ A,
                                                  const float* __restrict__ kscale,
                                                  const float* __restrict__ lscale,
                                                  float* __restrict__ out) {
    int tid = threadIdx.x;
    int r = tid & 63, sg = tid >> 6;
    int q0 = blockIdx.x * Q_TILE;
    float k = kscale[r];
    float a0 = A[(q0 + 0) * R_SZ + r] * k;
    float a1 = A[(q0 + 1) * R_SZ + r] * k;
    float a2 = A[(q0 + 2) * R_SZ + r] * k;
    float a3 = A[(q0 + 3) * R_SZ + r] * k;
    float c0 = 0.f, c1 = 0.f, c2 = 0.f, c3 = 0.f;
#pragma unroll 4
    for (int s = sg; s < B_SZ; s += 4) {
        float as = A[s * R_SZ + r] * k;
        float d;
        d = a0 - as; c0 += __expf(-d * d);
        d = a1 - as; c1 += __expf(-d * d);
        d = a2 - as; c2 += __expf(-d * d);
        d = a3 - as; c3 += __expf(-d * d);
    }
    __shared__ float lds[4][Q_TILE][64];   // [sg][t][r]
    lds[sg][0][r] = c0;
    lds[sg][1][r] = c1;
    lds[sg][2][r] = c2;
    lds[sg][3][r] = c3;
    __syncthreads();
    // each thread now owns one (t, r) pair: t = sg, r = r
    float S = lds[0][sg][r] + lds[1][sg][r] + lds[2][sg][r] + lds[3][sg][r];
    float dens = S * lscale[r];
    float v = __logf(dens + 1e-8f);
    // block-reduce v
    for (int off = 32; off > 0; off >>= 1) v += __shfl_down(v, off, 64);
    __shared__ float wred[4];
    if (r == 0) wred[sg] = v;
    __syncthreads();
    if (tid == 0) {
        float tot = (wred[0] + wred[1] + wred[2] + wred[3]) *
                    (1.0f / ((float)B_SZ * (float)R_SZ));
        atomicAdd(out, tot);   // loss_entropy = mean_{q,r} log(density+eps)
    }
}

extern "C" void kernel_launch(void* const* d_in, const int* in_sizes, int n_in,
                              void* d_out, int out_size, void* d_ws, size_t ws_size,
                              hipStream_t stream) {
    const float* A = (const float*)d_in[0];
    float* out = (float*)d_out;

    float* wsf = (float*)d_ws;
    float* mean   = wsf;            // 64
    float* kscale = wsf + 64;       // 64
    float* lscale = wsf + 128;      // 64
    float* G      = wsf + 192;      // 64*64

    // d_out and G are accumulated via atomics; both are poisoned before each call.
    hipMemsetAsync(d_out, 0, out_size * sizeof(float), stream);
    hipMemsetAsync((void*)G, 0, R_SZ * R_SZ * sizeof(float), stream);

    stats_kernel<<<R_SZ, 256, 0, stream>>>(A, mean, kscale, lscale);
    gram_kernel<<<dim3(R_SZ, 4), 256, 0, stream>>>(A, G);
    cov_finalize<<<R_SZ, 64, 0, stream>>>(G, mean, out);
    kde_kernel<<<B_SZ / Q_TILE, 256, 0, stream>>>(A, kscale, lscale, out);
}

// Round 2
// 104.085 us; speedup vs baseline: 1.2576x; 1.2576x over previous
//
#include <hip/hip_runtime.h>
#include <math.h>

#define B_SZ 2048
#define R_SZ 64
#define Q_TILE 4
#define SG_N 16            // sample groups per kde block (block = SG_N*64 threads)

// B^-0.2 for B=2048: 2^(-2.2)
#define B_POW_NEG02 0.217637640824031f
#define SQRT_2PI 2.5066282746310002f
#define LOG2E 1.44269504088896340736f

// native v_exp_f32 (exp2) — same OCML symbol HIP's fast-math path uses
extern "C" __device__ float __ocml_native_exp2_f32(float);

// ---------------------------------------------------------------------------
// Kernel 1: fused stats + Gram-row + covariance row.
// grid 64 blocks (one per receptor row i), 1024 threads.
// Computes: kscale[i], lscale[i] (Silverman bandwidth, exp2-prescaled),
//           cov_partial[i] = sum_{j != i} cov(i,j)^2
// ---------------------------------------------------------------------------
__global__ __launch_bounds__(1024) void cov_stats_kernel(const float* __restrict__ A,
                                                         float* __restrict__ kscale,
                                                         float* __restrict__ lscale,
                                                         float* __restrict__ cov_partial) {
    int i = blockIdx.x;
    int tid = threadIdx.x;
    int j = tid & 63, bg = tid >> 6;          // 16 b-groups

    float g = 0.f, sj = 0.f;
#pragma unroll 4
    for (int b = bg; b < B_SZ; b += SG_N) {
        float ai = A[b * R_SZ + i];           // wave-uniform broadcast (L1 hit)
        float aj = A[b * R_SZ + j];           // coalesced
        g = fmaf(ai, aj, g);
        sj += aj;
    }

    __shared__ float gred[SG_N][64];
    __shared__ float sred[SG_N][64];
    __shared__ float gfin[64], sfin[64];
    gred[bg][j] = g;
    sred[bg][j] = sj;
    __syncthreads();
    if (tid < 64) {                           // wave 0 only, lane = j
        float G = 0.f, S = 0.f;
#pragma unroll
        for (int t = 0; t < SG_N; ++t) { G += gred[t][j]; S += sred[t][j]; }
        gfin[j] = G;
        sfin[j] = S;
    }
    __syncthreads();
    if (tid < 64) {
        float m_j = sfin[j] * (1.f / (float)B_SZ);
        float m_i = sfin[i] * (1.f / (float)B_SZ);
        float cov = (gfin[j] - (float)B_SZ * m_i * m_j) * (1.f / (float)(B_SZ - 1));
        float v = (j == i) ? 0.f : cov * cov;
        for (int off = 32; off > 0; off >>= 1) v += __shfl_down(v, off, 64);
        if (j == 0) cov_partial[i] = v;
        if (j == i) {
            // var with ddof=1: (sum a^2 - S*m) / (B-1); sum a^2 = Gram diagonal
            float var = (gfin[i] - sfin[i] * m_i) * (1.f / (float)(B_SZ - 1));
            var = fmaxf(var, 0.f);
            float h = fmaxf(1.06f * sqrtf(var) * B_POW_NEG02, 1e-4f);
            // prescale so kde arg is exp2(-(dk)^2) = exp(-0.5*(d/h)^2)
            kscale[i] = sqrtf(0.5f * LOG2E) / h;
            lscale[i] = 1.0f / ((float)B_SZ * h * SQRT_2PI);
        }
    }
}

// ---------------------------------------------------------------------------
// Kernel 2: pairwise KDE + entropy partial per block.
// grid 512 blocks x 1024 threads (16 waves) -> 8192 waves = 100% occupancy.
// Block handles Q_TILE=4 query rows; lane = receptor r (coalesced row loads);
// 16 sample-groups stride the s loop (128 iters, 4 exps each).
// ---------------------------------------------------------------------------
__global__ __launch_bounds__(1024) void kde_kernel(const float* __restrict__ A,
                                                   const float* __restrict__ kscale,
                                                   const float* __restrict__ lscale,
                                                   float* __restrict__ kde_partial) {
    int tid = threadIdx.x;
    int r = tid & 63, sg = tid >> 6;          // sg = wave index, 0..15
    int q0 = blockIdx.x * Q_TILE;
    float k = kscale[r];
    float a0 = A[(q0 + 0) * R_SZ + r] * k;
    float a1 = A[(q0 + 1) * R_SZ + r] * k;
    float a2 = A[(q0 + 2) * R_SZ + r] * k;
    float a3 = A[(q0 + 3) * R_SZ + r] * k;
    float c0 = 0.f, c1 = 0.f, c2 = 0.f, c3 = 0.f;
#pragma unroll 4
    for (int s = sg; s < B_SZ; s += SG_N) {
        float as = A[s * R_SZ + r] * k;
        float d;
        d = a0 - as; c0 += __ocml_native_exp2_f32(-d * d);
        d = a1 - as; c1 += __ocml_native_exp2_f32(-d * d);
        d = a2 - as; c2 += __ocml_native_exp2_f32(-d * d);
        d = a3 - as; c3 += __ocml_native_exp2_f32(-d * d);
    }
    __shared__ float lds[SG_N][Q_TILE][64];
    lds[sg][0][r] = c0;
    lds[sg][1][r] = c1;
    lds[sg][2][r] = c2;
    lds[sg][3][r] = c3;
    __syncthreads();
    __shared__ float wred[Q_TILE];
    if (sg < Q_TILE) {                        // waves 0..3: wave sg owns query-row sg
        float S = 0.f;
#pragma unroll
        for (int t = 0; t < SG_N; ++t) S += lds[t][sg][r];
        float v = __logf(fmaf(S, lscale[r], 1e-8f));
        for (int off = 32; off > 0; off >>= 1) v += __shfl_down(v, off, 64);
        if (r == 0) wred[sg] = v;
    }
    __syncthreads();
    if (tid == 0) {
        kde_partial[blockIdx.x] = (wred[0] + wred[1] + wred[2] + wred[3]) *
                                  (1.0f / ((float)B_SZ * (float)R_SZ));
    }
}

// ---------------------------------------------------------------------------
// Kernel 3: sum the 64 cov partials + 512 kde partials (contiguous in ws),
// single write to out[0]. No memset of d_out needed.
// ---------------------------------------------------------------------------
__global__ __launch_bounds__(256) void final_kernel(const float* __restrict__ partials,
                                                    int n, float* __restrict__ out) {
    int tid = threadIdx.x;
    float v = 0.f;
    for (int idx = tid; idx < n; idx += 256) v += partials[idx];
    for (int off = 32; off > 0; off >>= 1) v += __shfl_down(v, off, 64);
    __shared__ float wr[4];
    int wave = tid >> 6, lane = tid & 63;
    if (lane == 0) wr[wave] = v;
    __syncthreads();
    if (tid == 0) out[0] = wr[0] + wr[1] + wr[2] + wr[3];
}

extern "C" void kernel_launch(void* const* d_in, const int* in_sizes, int n_in,
                              void* d_out, int out_size, void* d_ws, size_t ws_size,
                              hipStream_t stream) {
    const float* A = (const float*)d_in[0];
    float* out = (float*)d_out;

    float* wsf = (float*)d_ws;
    float* kscale      = wsf;           // 64
    float* lscale      = wsf + 64;      // 64
    float* cov_partial = wsf + 128;     // 64   \ contiguous 576-float
    float* kde_partial = wsf + 192;     // 512  / partial block

    cov_stats_kernel<<<R_SZ, 1024, 0, stream>>>(A, kscale, lscale, cov_partial);
    kde_kernel<<<B_SZ / Q_TILE, 1024, 0, stream>>>(A, kscale, lscale, kde_partial);
    final_kernel<<<1, 256, 0, stream>>>(cov_partial, 64 + B_SZ / Q_TILE, out);
}